// Round 1
// baseline (10336.380 us; speedup 1.0000x reference)
//
#include <hip/hip_runtime.h>
#include <hip/hip_fp16.h>

#define N_VAR 256
#define M_CON 512
#define BATCH 64
#define SIGMA_C 1e-6f
#define RHO_C 0.1f
#define ALPHA_C 1.6f
#define NITERS 500

// ---------------------------------------------------------------------------
// K1: transpose A [512][256] -> At [256][512] per batch
// ---------------------------------------------------------------------------
__global__ __launch_bounds__(256) void k_transpose(const float* __restrict__ A,
                                                   float* __restrict__ At) {
  __shared__ float tile[32][33];
  int b = blockIdx.z;
  int n0 = blockIdx.x * 32;   // 256/32 = 8
  int m0 = blockIdx.y * 32;   // 512/32 = 16
  const float* Ab = A + (size_t)b * (M_CON * N_VAR);
  float* Atb = At + (size_t)b * (M_CON * N_VAR);
  int tx = threadIdx.x, ty = threadIdx.y;  // (32, 8)
#pragma unroll
  for (int j = 0; j < 32; j += 8)
    tile[ty + j][tx] = Ab[(size_t)(m0 + ty + j) * N_VAR + n0 + tx];
  __syncthreads();
#pragma unroll
  for (int j = 0; j < 32; j += 8)
    Atb[(size_t)(n0 + ty + j) * M_CON + m0 + tx] = tile[tx][ty + j];
}

// ---------------------------------------------------------------------------
// K2: batched NT GEMM  C[i][j] = alpha * sum_k X[i][k]*Y[j][k]  (+ diag)
// 128x128 tile per WG, 256 threads, 8x8 accumulators, K staged in LDS by 16.
// I, J, K multiples of 128/128/16. Used for Mk, F, G.
// ---------------------------------------------------------------------------
__global__ __launch_bounds__(256) void k_ntgemm(
    const float* __restrict__ X, const float* __restrict__ Y,
    float* __restrict__ C, int I, int J, int K,
    long long bsX, long long bsY, long long bsC, float alpha,
    const float* __restrict__ diagv, int tilesJ) {
  int b = blockIdx.y;
  int ti = blockIdx.x / tilesJ, tj = blockIdx.x % tilesJ;
  int i0 = ti * 128, j0 = tj * 128;
  const float* Xb = X + (size_t)b * bsX;
  const float* Yb = Y + (size_t)b * bsY;
  float* Cb = C + (size_t)b * bsC;
  __shared__ float Xs[16][128];
  __shared__ float Ys[16][128];
  int tid = threadIdx.x;
  int tx = tid & 15, ty = tid >> 4;
  float acc[8][8];
#pragma unroll
  for (int r = 0; r < 8; ++r)
#pragma unroll
    for (int c = 0; c < 8; ++c) acc[r][c] = 0.0f;

  for (int kk = 0; kk < K; kk += 16) {
    // stage 128 rows x 16 k for each operand; 512 float4 per operand
#pragma unroll
    for (int v = 0; v < 2; ++v) {
      int idx = v * 256 + tid;       // 0..511, lane-consecutive float4
      int row = idx >> 2;            // 0..127
      int k4 = (idx & 3) * 4;
      float4 gx = *(const float4*)(Xb + (size_t)(i0 + row) * K + kk + k4);
      Xs[k4 + 0][row] = gx.x; Xs[k4 + 1][row] = gx.y;
      Xs[k4 + 2][row] = gx.z; Xs[k4 + 3][row] = gx.w;
      float4 gy = *(const float4*)(Yb + (size_t)(j0 + row) * K + kk + k4);
      Ys[k4 + 0][row] = gy.x; Ys[k4 + 1][row] = gy.y;
      Ys[k4 + 2][row] = gy.z; Ys[k4 + 3][row] = gy.w;
    }
    __syncthreads();
#pragma unroll
    for (int k = 0; k < 16; ++k) {
      float xr[8], yr[8];
      *(float4*)&xr[0] = *(float4*)&Xs[k][ty * 8];
      *(float4*)&xr[4] = *(float4*)&Xs[k][ty * 8 + 4];
      *(float4*)&yr[0] = *(float4*)&Ys[k][tx * 8];
      *(float4*)&yr[4] = *(float4*)&Ys[k][tx * 8 + 4];
#pragma unroll
      for (int r = 0; r < 8; ++r)
#pragma unroll
        for (int c = 0; c < 8; ++c) acc[r][c] += xr[r] * yr[c];
    }
    __syncthreads();
  }
#pragma unroll
  for (int r = 0; r < 8; ++r) {
    int gi = i0 + ty * 8 + r;
#pragma unroll
    for (int c = 0; c < 8; ++c) {
      int gj = j0 + tx * 8 + c;
      float val = acc[r][c] * alpha;
      if (diagv != nullptr && gi == gj) val += diagv[(size_t)b * N_VAR + gi] + SIGMA_C;
      Cb[(size_t)gi * J + gj] = val;
    }
  }
}

// ---------------------------------------------------------------------------
// K3: in-place Gauss-Jordan inversion (no pivoting; Mk is SPD, diag-dominant).
// One WG of 1024 threads per batch. Thread t owns column c=t&255, rows 4j+(t>>8).
// Matrix held entirely in registers (64 floats/thread).
// ---------------------------------------------------------------------------
__global__ __launch_bounds__(1024) void k_invert(const float* __restrict__ Mk,
                                                 float* __restrict__ Mi) {
  int b = blockIdx.x;
  const float* src = Mk + (size_t)b * 65536;
  float* dst = Mi + (size_t)b * 65536;
  int t = threadIdx.x;
  int c = t & 255, rq = t >> 8;
  float a[64];
#pragma unroll
  for (int j = 0; j < 64; ++j) a[j] = src[j * 1024 + t];  // row 4j+rq, col c

  // colP permuted layout: colP[j + 64*rq] = column-k value at row 4j+rq
  __shared__ float colP[2][256];
  __shared__ float rowB[2][256];

  for (int k = 0; k < 256; ++k) {
    int cur = k & 1;
    int kj = k >> 2, kq = k & 3;
    if (c == k) {
      float4* cp4 = (float4*)&colP[cur][64 * rq];
#pragma unroll
      for (int jj = 0; jj < 16; ++jj)
        cp4[jj] = make_float4(a[4 * jj], a[4 * jj + 1], a[4 * jj + 2], a[4 * jj + 3]);
    }
    __syncthreads();
    float pivinv = 1.0f / colP[cur][kj + 64 * kq];
    if (rq == kq) {  // these threads own one element of pivot row k (at j=kj)
      float v = (c == k) ? pivinv : a[kj] * pivinv;
      a[kj] = v;
      rowB[cur][c] = v;
    }
    __syncthreads();
    float rb = rowB[cur][c];
    float keep = a[kj];  // scaled pivot-row element (only meaningful if rq==kq)
    const float4* cp4 = (const float4*)&colP[cur][64 * rq];
#pragma unroll
    for (int jj = 0; jj < 16; ++jj) {
      float4 cv = cp4[jj];
      a[4 * jj + 0] -= rb * cv.x;
      a[4 * jj + 1] -= rb * cv.y;
      a[4 * jj + 2] -= rb * cv.z;
      a[4 * jj + 3] -= rb * cv.w;
    }
    if (rq == kq) a[kj] = keep;  // pivot row is not eliminated
    if (c == k) {                // pivot column: a[i][k] = -pivinv * dum_i
#pragma unroll
      for (int jj = 0; jj < 16; ++jj) {
        float4 cv = cp4[jj];
        a[4 * jj + 0] = -pivinv * cv.x;
        a[4 * jj + 1] = -pivinv * cv.y;
        a[4 * jj + 2] = -pivinv * cv.z;
        a[4 * jj + 3] = -pivinv * cv.w;
      }
      if (rq == kq) a[kj] = pivinv;  // a[k][k] = pivinv
    }
  }
#pragma unroll
  for (int j = 0; j < 64; ++j) dst[j * 1024 + t] = a[j];
}

// ---------------------------------------------------------------------------
// K4a: h = Minv * q   (column access via symmetry; coalesced)
// ---------------------------------------------------------------------------
__global__ __launch_bounds__(256) void k_matvec_h(const float* __restrict__ Mi,
                                                  const float* __restrict__ q,
                                                  float* __restrict__ h) {
  int b = blockIdx.x, t = threadIdx.x;
  __shared__ float qs[256];
  qs[t] = q[(size_t)b * 256 + t];
  __syncthreads();
  const float* Mb = Mi + (size_t)b * 65536;
  float acc = 0.0f;
  for (int k = 0; k < 256; ++k) acc += Mb[(size_t)k * 256 + t] * qs[k];
  h[(size_t)b * 256 + t] = acc;
}

// K4b: d = A * h  via At columns (coalesced)
__global__ __launch_bounds__(512) void k_matvec_d(const float* __restrict__ At,
                                                  const float* __restrict__ h,
                                                  float* __restrict__ d) {
  int b = blockIdx.x, t = threadIdx.x;
  __shared__ float hs[256];
  if (t < 256) hs[t] = h[(size_t)b * 256 + t];
  __syncthreads();
  const float* Ab = At + (size_t)b * 131072;
  float acc = 0.0f;
  for (int n = 0; n < 256; ++n) acc += Ab[(size_t)n * 512 + t] * hs[n];
  d[(size_t)b * 512 + t] = acc;
}

// ---------------------------------------------------------------------------
// K5: persistent ADMM loop. One WG (1024 thr) per batch; z,y,S,l,u,d in LDS.
//   w = rho*z - y ; S = (1-alpha)*S + w ; zt = G*w - d ;
//   zh = alpha*zt + (1-alpha)*z ; z = clip(zh + y/rho, l, u) ; y += rho*(zh-z)
// Final: x = Minv*(alpha*At*S - q)   (exact collapse of the x recursion)
// G symmetric -> read G[c][m] with m lane-fast (fully coalesced float4).
// ---------------------------------------------------------------------------
__global__ __launch_bounds__(1024) void k_admm(
    const float* __restrict__ G, const float* __restrict__ dvec,
    const float* __restrict__ lv, const float* __restrict__ uv,
    const float* __restrict__ A, const float* __restrict__ q,
    const float* __restrict__ Mi, float* __restrict__ xout) {
  int b = blockIdx.x, t = threadIdx.x;
  __shared__ float z[512], y[512], Sv[512], ls[512], us[512], dsh[512], w[512];
  __shared__ float part[8][512];
  __shared__ float uu[256];
  if (t < 512) {
    z[t] = 0.0f; y[t] = 0.0f; Sv[t] = 0.0f;
    ls[t] = lv[(size_t)b * 512 + t];
    us[t] = uv[(size_t)b * 512 + t];
    dsh[t] = dvec[(size_t)b * 512 + t];
  }
  __syncthreads();

  const float* Gb = G + (size_t)b * 262144;
  int mg = t & 127, Kc = t >> 7;           // output rows 4*mg.., col-chunk Kc
  const float* gcol = Gb + 4 * mg;

  for (int it = 0; it < NITERS; ++it) {
    if (t < 512) {
      float wv = RHO_C * z[t] - y[t];
      w[t] = wv;
      Sv[t] = wv - 0.6f * Sv[t];           // S = (1-alpha)*S + w, 1-alpha = -0.6
    }
    __syncthreads();
    float a0 = 0.0f, a1 = 0.0f, a2 = 0.0f, a3 = 0.0f;
#pragma unroll 4
    for (int s = 0; s < 64; ++s) {
      int cI = Kc * 64 + s;
      float4 g = *(const float4*)(gcol + (size_t)cI * 512);
      float wc = w[cI];
      a0 += g.x * wc; a1 += g.y * wc; a2 += g.z * wc; a3 += g.w * wc;
    }
    *(float4*)&part[Kc][4 * mg] = make_float4(a0, a1, a2, a3);
    __syncthreads();
    if (t < 512) {
      float zt = part[0][t] + part[1][t] + part[2][t] + part[3][t] +
                 part[4][t] + part[5][t] + part[6][t] + part[7][t] - dsh[t];
      float zh = ALPHA_C * zt + (1.0f - ALPHA_C) * z[t];
      float zc = zh + y[t] * (1.0f / RHO_C);
      zc = fminf(fmaxf(zc, ls[t]), us[t]);
      y[t] += RHO_C * (zh - zc);
      z[t] = zc;
    }
    __syncthreads();
  }

  // u = alpha * A^T S - q   (A column access, coalesced)
  {
    int n = t & 255, K2 = t >> 8;
    const float* Ab = A + (size_t)b * 131072;
    float acc = 0.0f;
    for (int mm = 0; mm < 128; ++mm) {
      int m = K2 * 128 + mm;
      acc += Ab[(size_t)m * 256 + n] * Sv[m];
    }
    part[K2][n] = acc;
  }
  __syncthreads();
  if (t < 256)
    uu[t] = ALPHA_C * (part[0][t] + part[1][t] + part[2][t] + part[3][t]) -
            q[(size_t)b * 256 + t];
  __syncthreads();
  // x = Minv * u  (column access via symmetry)
  {
    int n = t & 255, K2 = t >> 8;
    const float* Mb = Mi + (size_t)b * 65536;
    float acc = 0.0f;
    for (int kk = 0; kk < 64; ++kk) {
      int kidx = K2 * 64 + kk;
      acc += Mb[(size_t)kidx * 256 + n] * uu[kidx];
    }
    part[K2][n] = acc;
  }
  __syncthreads();
  if (t < 256)
    xout[(size_t)b * 256 + t] =
        part[0][t] + part[1][t] + part[2][t] + part[3][t];
}

// ---------------------------------------------------------------------------
extern "C" void kernel_launch(void* const* d_in, const int* in_sizes, int n_in,
                              void* d_out, int out_size, void* d_ws, size_t ws_size,
                              hipStream_t stream) {
  (void)in_sizes; (void)n_in; (void)out_size; (void)ws_size;
  const float* P = (const float*)d_in[0];
  const float* q = (const float*)d_in[1];
  const float* Av = (const float*)d_in[2];
  const float* lv = (const float*)d_in[3];
  const float* uv = (const float*)d_in[4];
  float* xout = (float*)d_out;

  // workspace layout (floats). At dies after k_matvec_d -> F aliases At.
  // Mk dies after k_invert -> G overlaps Mk and beyond. Total ~117.6 MB.
  float* ws = (float*)d_ws;
  float* At = ws;                       // [0,      8388608)  64*256*512
  float* F  = ws;                       // alias of At
  float* Mi = ws + 8388608;             // [8.39M, 12.58M)   64*256*256
  float* Mk = ws + 12582912;            // [12.58M,16.78M)   64*256*256
  float* G  = ws + 12582912;            // [12.58M,29.36M)   64*512*512 (over dead Mk)
  float* hv = ws + 29360128;            // 64*256
  float* dv = ws + 29376512;            // 64*512

  k_transpose<<<dim3(8, 16, 64), dim3(32, 8), 0, stream>>>(Av, At);
  // Mk = rho*A^T A + diag(P + sigma)
  k_ntgemm<<<dim3(4, 64), 256, 0, stream>>>(At, At, Mk, 256, 256, 512,
                                            131072LL, 131072LL, 65536LL,
                                            RHO_C, P, 2);
  k_invert<<<64, 1024, 0, stream>>>(Mk, Mi);
  k_matvec_h<<<64, 256, 0, stream>>>(Mi, q, hv);
  k_matvec_d<<<64, 512, 0, stream>>>(At, hv, dv);   // uses At before overwrite
  // F = A * Minv  (NT with symmetric Minv)
  k_ntgemm<<<dim3(8, 64), 256, 0, stream>>>(Av, Mi, F, 512, 256, 256,
                                            131072LL, 65536LL, 131072LL,
                                            1.0f, nullptr, 2);
  // G = F * A^T
  k_ntgemm<<<dim3(16, 64), 256, 0, stream>>>(F, Av, G, 512, 512, 256,
                                             131072LL, 131072LL, 262144LL,
                                             1.0f, nullptr, 4);
  k_admm<<<64, 1024, 0, stream>>>(G, dv, lv, uv, Av, q, Mi, xout);
}